// Round 4
// baseline (328.365 us; speedup 1.0000x reference)
//
#include <hip/hip_runtime.h>
#include <cstdint>

#define L_SEQ 1024
#define DSRC 512
#define XPL 2097152L   // x/proj plane stride (elems) = 2048*1024
#define WPL 1048576L   // weight plane stride = 1024*1024

typedef __attribute__((ext_vector_type(8))) short short8;
typedef __attribute__((ext_vector_type(4))) float floatx4;

__device__ __forceinline__ unsigned short f2bf(float f) {
  unsigned int x = __float_as_uint(f);
  x += 0x7fff + ((x >> 16) & 1);   // RNE
  return (unsigned short)(x >> 16);
}
__device__ __forceinline__ float bf2f(unsigned short h) {
  return __uint_as_float((unsigned)h << 16);
}
// 3-way bf16 split: f = h0 + h1 + h2 + O(2^-27 |f|)
__device__ __forceinline__ void split3(float f, unsigned short* h) {
  h[0] = f2bf(f);
  float d = f - bf2f(h[0]);
  h[1] = f2bf(d);
  h[2] = f2bf(d - bf2f(h[1]));
}

// async global->LDS, 16B per lane. LDS dest = wave-uniform base + lane*16.
__device__ __forceinline__ void gll16(const void* g, void* l) {
  __builtin_amdgcn_global_load_lds(
      (const __attribute__((address_space(1))) void*)(uintptr_t)g,
      (__attribute__((address_space(3))) void*)(uint32_t)(uintptr_t)l,
      16, 0, 0);
}

// ---------------- split the 4 fp32 inputs into 3 bf16 planes each ----------------
__global__ __launch_bounds__(256) void split_inputs_k(
    const float* __restrict__ query, const float* __restrict__ key_t,
    const float* __restrict__ wq, const float* __restrict__ wk,
    ushort* __restrict__ xs, ushort* __restrict__ wsp) {
  int blk = blockIdx.x;
  const float* in; ushort* out; long pl; int idx;
  if (blk < 2048)      { in = query; out = xs;            pl = XPL; idx = blk; }
  else if (blk < 4096) { in = key_t; out = xs + 3 * XPL;  pl = XPL; idx = blk - 2048; }
  else if (blk < 5120) { in = wq;    out = wsp;           pl = WPL; idx = blk - 4096; }
  else                 { in = wk;    out = wsp + 3 * WPL; pl = WPL; idx = blk - 5120; }
  long e = (long)idx * 1024 + threadIdx.x * 4;
  float4 v = *(const float4*)(in + e);
  unsigned short h0[3], h1[3], h2[3], h3[3];
  split3(v.x, h0); split3(v.y, h1); split3(v.z, h2); split3(v.w, h3);
#pragma unroll
  for (int s = 0; s < 3; s++) {
    ushort4 u; u.x = h0[s]; u.y = h1[s]; u.z = h2[s]; u.w = h3[s];
    *(ushort4*)(out + s * pl + e) = u;
  }
}

// ---------------- projection GEMM: planes(X * W^T + bias), bf16x6 emulated fp32 ----------------
// Tile 128(M) x 64(N), BK=32, 256 threads = 4 waves (2x2), wave tile 64x32.
// Staging via global_load_lds width=16 (m97 structure). Epilogue writes the
// 3 bf16 planes of the fp32 result directly (consumed by score_gemm_k).
__global__ __launch_bounds__(256) void proj_gemm_k(
    const ushort* __restrict__ xs, const ushort* __restrict__ wsp,
    ushort* __restrict__ out, const float* __restrict__ bq, const float* __restrict__ bk) {
  __shared__ ushort As[3][4096];   // [plane][128 rows * 32 cols]
  __shared__ ushort Bs[3][2048];   // [plane][64 rows * 32 cols]
  int z = blockIdx.z;
  const ushort* Ag = xs + (long)z * 3 * XPL + (long)blockIdx.y * 128 * 1024;
  const ushort* Bg = wsp + (long)z * 3 * WPL + (long)blockIdx.x * 64 * 1024;
  const float* bias = z ? bk : bq;

  int tid = threadIdx.x;
  int lane = tid & 63, wv = tid >> 6;
  int wm = wv >> 1, wn = wv & 1;
  int quad = lane >> 4, l16 = lane & 15;

  int srow = lane >> 2;        // staging: row within 16-row group
  int scol = (lane & 3) * 8;   // staging: col (8 bf16 = 16B)

  floatx4 acc[4][2] = {};

  for (int k0 = 0; k0 < 1024; k0 += 32) {
#pragma unroll
    for (int s = 0; s < 3; s++) {
#pragma unroll
      for (int c = 0; c < 2; c++) {
        int r0 = wv * 32 + c * 16;
        gll16(Ag + (long)s * XPL + (long)(r0 + srow) * 1024 + k0 + scol,
              &As[s][r0 * 32]);
      }
      int r0b = wv * 16;
      gll16(Bg + (long)s * WPL + (long)(r0b + srow) * 1024 + k0 + scol,
            &Bs[s][r0b * 32]);
    }
    __syncthreads();   // drain global_load_lds + barrier

    short8 af[3][4];
#pragma unroll
    for (int s = 0; s < 3; s++)
#pragma unroll
      for (int i = 0; i < 4; i++)
        af[s][i] = *(const short8*)(&As[s][(wm * 64 + i * 16 + l16) * 32 + quad * 8]);
#pragma unroll
    for (int j = 0; j < 2; j++) {
      int boff = (wn * 32 + j * 16 + l16) * 32 + quad * 8;
      short8 b0 = *(const short8*)(&Bs[0][boff]);
      short8 b1 = *(const short8*)(&Bs[1][boff]);
      short8 b2 = *(const short8*)(&Bs[2][boff]);
#pragma unroll
      for (int i = 0; i < 4; i++) {
        // small -> large accumulation
        acc[i][j] = __builtin_amdgcn_mfma_f32_16x16x32_bf16(af[1][i], b1, acc[i][j], 0, 0, 0);
        acc[i][j] = __builtin_amdgcn_mfma_f32_16x16x32_bf16(af[0][i], b2, acc[i][j], 0, 0, 0);
        acc[i][j] = __builtin_amdgcn_mfma_f32_16x16x32_bf16(af[2][i], b0, acc[i][j], 0, 0, 0);
        acc[i][j] = __builtin_amdgcn_mfma_f32_16x16x32_bf16(af[0][i], b1, acc[i][j], 0, 0, 0);
        acc[i][j] = __builtin_amdgcn_mfma_f32_16x16x32_bf16(af[1][i], b0, acc[i][j], 0, 0, 0);
        acc[i][j] = __builtin_amdgcn_mfma_f32_16x16x32_bf16(af[0][i], b0, acc[i][j], 0, 0, 0);
      }
    }
    __syncthreads();   // protect LDS before next stage
  }

  ushort* Pg = out + (long)z * 3 * XPL;
#pragma unroll
  for (int j = 0; j < 2; j++) {
    int col = blockIdx.x * 64 + wn * 32 + j * 16 + l16;
    float bv = bias[col];
#pragma unroll
    for (int i = 0; i < 4; i++) {
#pragma unroll
      for (int r = 0; r < 4; r++) {
        int row = blockIdx.y * 128 + wm * 64 + i * 16 + quad * 4 + r;
        unsigned short h[3];
        split3(acc[i][j][r] + bv, h);
#pragma unroll
        for (int s = 0; s < 3; s++)
          Pg[(long)s * XPL + (long)row * 1024 + col] = h[s];
      }
    }
  }
}

// ---------------- score GEMM: S = q_v * k_v^T for one batch b, pure bf16x6 ----------------
// Tile 128x128, K=128, BK=32, 256 threads = 4 waves (2x2), wave tile 64x64.
__global__ __launch_bounds__(256) void score_gemm_k(
    const ushort* __restrict__ ps, float* __restrict__ S, int b) {
  __shared__ ushort As[3][4096];
  __shared__ ushort Bs[3][4096];
  int v = blockIdx.z;
  const ushort* Ag = ps + (long)(b * 1024 + blockIdx.y * 128) * 1024 + v * 128;
  const ushort* Bg = ps + 3 * XPL + (long)(b * 1024 + blockIdx.x * 128) * 1024 + v * 128;

  int tid = threadIdx.x;
  int lane = tid & 63, wv = tid >> 6;
  int wm = wv >> 1, wn = wv & 1;
  int quad = lane >> 4, l16 = lane & 15;

  int srow = lane >> 2;
  int scol = (lane & 3) * 8;

  floatx4 acc[4][4] = {};

  for (int k0 = 0; k0 < 128; k0 += 32) {
#pragma unroll
    for (int s = 0; s < 3; s++) {
#pragma unroll
      for (int c = 0; c < 2; c++) {
        int r0 = wv * 32 + c * 16;
        gll16(Ag + (long)s * XPL + (long)(r0 + srow) * 1024 + k0 + scol,
              &As[s][r0 * 32]);
        gll16(Bg + (long)s * XPL + (long)(r0 + srow) * 1024 + k0 + scol,
              &Bs[s][r0 * 32]);
      }
    }
    __syncthreads();

    short8 af[3][4];
#pragma unroll
    for (int s = 0; s < 3; s++)
#pragma unroll
      for (int i = 0; i < 4; i++)
        af[s][i] = *(const short8*)(&As[s][(wm * 64 + i * 16 + l16) * 32 + quad * 8]);
#pragma unroll
    for (int j = 0; j < 4; j++) {
      int boff = (wn * 64 + j * 16 + l16) * 32 + quad * 8;
      short8 b0 = *(const short8*)(&Bs[0][boff]);
      short8 b1 = *(const short8*)(&Bs[1][boff]);
      short8 b2 = *(const short8*)(&Bs[2][boff]);
#pragma unroll
      for (int i = 0; i < 4; i++) {
        acc[i][j] = __builtin_amdgcn_mfma_f32_16x16x32_bf16(af[1][i], b1, acc[i][j], 0, 0, 0);
        acc[i][j] = __builtin_amdgcn_mfma_f32_16x16x32_bf16(af[0][i], b2, acc[i][j], 0, 0, 0);
        acc[i][j] = __builtin_amdgcn_mfma_f32_16x16x32_bf16(af[2][i], b0, acc[i][j], 0, 0, 0);
        acc[i][j] = __builtin_amdgcn_mfma_f32_16x16x32_bf16(af[0][i], b1, acc[i][j], 0, 0, 0);
        acc[i][j] = __builtin_amdgcn_mfma_f32_16x16x32_bf16(af[1][i], b0, acc[i][j], 0, 0, 0);
        acc[i][j] = __builtin_amdgcn_mfma_f32_16x16x32_bf16(af[0][i], b0, acc[i][j], 0, 0, 0);
      }
    }
    __syncthreads();
  }

  float* Sb = S + (long)v * 1048576;
#pragma unroll
  for (int j = 0; j < 4; j++) {
    int col = blockIdx.x * 128 + wn * 64 + j * 16 + l16;
#pragma unroll
    for (int i = 0; i < 4; i++) {
#pragma unroll
      for (int r = 0; r < 4; r++) {
        int row = blockIdx.y * 128 + wm * 64 + i * 16 + quad * 4 + r;
        Sb[(long)row * 1024 + col] = acc[i][j][r];
      }
    }
  }
}

// ---------------- top-8 + softmax, one wave per q-row (8192 rows per launch) ----------------
__global__ __launch_bounds__(256) void topk_softmax_k(const float* __restrict__ scores,
                                                      float* __restrict__ wts,
                                                      int* __restrict__ idxs) {
  int row = blockIdx.x * 4 + (threadIdx.x >> 6);
  int lane = threadIdx.x & 63;
  const float* s = scores + (long)row * 1024;
  float v[16];
#pragma unroll
  for (int i = 0; i < 16; i++) v[i] = s[lane + i * 64];

  float topv[8]; int topi[8];
  for (int t = 0; t < 8; t++) {
    float bv = -1e30f; int bi = 1 << 30; int bslot = -1;
#pragma unroll
    for (int i = 0; i < 16; i++) {
      int ci = lane + i * 64;
      if (v[i] > bv) { bv = v[i]; bi = ci; bslot = i; }
    }
    float rv = bv; int ri = bi;
    for (int off = 32; off; off >>= 1) {
      float ov = __shfl_down(rv, off);
      int oi = __shfl_down(ri, off);
      if (ov > rv || (ov == rv && oi < ri)) { rv = ov; ri = oi; }
    }
    rv = __shfl(rv, 0); ri = __shfl(ri, 0);
    topv[t] = rv; topi[t] = ri;
    if (bslot >= 0 && bi == ri) v[bslot] = -1e30f;
  }
  float m = topv[0], sum = 0.f, e[8];
#pragma unroll
  for (int t = 0; t < 8; t++) { e[t] = __expf(topv[t] - m); sum += e[t]; }
  float inv = 1.0f / sum;
  if (lane < 8) {
    wts[(long)row * 8 + lane] = e[lane] * inv;
    idxs[(long)row * 8 + lane] = topi[lane];
  }
}

// ---------------- gather + weighted sum ----------------
// out[b,v,q,w,d] = sum_k wt[k] * source[b, idx_k + w - 1, d]   (zero OOB)
__global__ __launch_bounds__(256) void gather_out_k(const float* __restrict__ src,
                                                    const float* __restrict__ wts,
                                                    const int* __restrict__ idxs,
                                                    float* __restrict__ out) {
  int rowid = blockIdx.x;
  int b = rowid >> 13;
  int tid = threadIdx.x;
  int d4 = tid & 127;
  int w0 = (tid >> 7) << 1;
  const float4* s4 = (const float4*)src + (long)b * (L_SEQ * (DSRC / 4));
  float wt[8]; int id[8];
#pragma unroll
  for (int k = 0; k < 8; k++) {
    wt[k] = wts[(long)rowid * 8 + k];
    id[k] = idxs[(long)rowid * 8 + k];
  }
  float ax = 0, ay = 0, az = 0, aw = 0;
  float bx = 0, by = 0, bz2 = 0, bw = 0;
#pragma unroll
  for (int k = 0; k < 8; k++) {
    int r0 = id[k] + w0 - 1;
    if ((unsigned)r0 < (unsigned)L_SEQ) {
      float4 x = s4[(long)r0 * 128 + d4];
      ax += wt[k] * x.x; ay += wt[k] * x.y; az += wt[k] * x.z; aw += wt[k] * x.w;
    }
    int r1 = r0 + 1;
    if ((unsigned)r1 < (unsigned)L_SEQ) {
      float4 x = s4[(long)r1 * 128 + d4];
      bx += wt[k] * x.x; by += wt[k] * x.y; bz2 += wt[k] * x.z; bw += wt[k] * x.w;
    }
  }
  float4* o4 = (float4*)out + ((long)rowid * 4 + w0) * 128 + d4;
  o4[0] = make_float4(ax, ay, az, aw);
  o4[128] = make_float4(bx, by, bz2, bw);
}

extern "C" void kernel_launch(void* const* d_in, const int* in_sizes, int n_in,
                              void* d_out, int out_size, void* d_ws, size_t ws_size,
                              hipStream_t stream) {
  (void)in_sizes; (void)n_in; (void)out_size; (void)ws_size;
  const float* query  = (const float*)d_in[0];
  const float* key_t  = (const float*)d_in[1];
  const float* source = (const float*)d_in[2];
  const float* wq     = (const float*)d_in[3];
  const float* bq     = (const float*)d_in[4];
  const float* wk     = (const float*)d_in[5];
  const float* bk     = (const float*)d_in[6];

  char* ws = (char*)d_ws;
  // ws layout (bytes), total 63,963,136 (< R1's proven 84,934,656 footprint):
  //   0         xs: 6 bf16 planes (xq,xk)          24 MB  dead after proj
  //   25165824  wsp: 6 bf16 planes (wq,wk)         12 MB  dead after proj
  //   0         scores fp32 (8x1024x1024, 1 batch) 32 MB  (aliases xs)
  //   37748736  qs/ks: 6 bf16 planes of proj out   24 MB  live: proj -> score
  //   62914560  wts fp32 (16384x8)                 512 KB
  //   63438848  idxs i32 (16384x8)                 512 KB
  ushort* xs  = (ushort*)(ws + 0);
  ushort* wsp = (ushort*)(ws + 25165824);
  float*  sc  = (float*)(ws + 0);
  ushort* qs  = (ushort*)(ws + 37748736);
  float*  wts = (float*)(ws + 62914560);
  int*   idxs = (int*)(ws + 63438848);

  split_inputs_k<<<6144, 256, 0, stream>>>(query, key_t, wq, wk, xs, wsp);
  proj_gemm_k<<<dim3(16, 16, 2), 256, 0, stream>>>(xs, wsp, qs, bq, bk);
  for (int b = 0; b < 2; b++) {
    score_gemm_k<<<dim3(8, 8, 8), 256, 0, stream>>>(qs, sc, b);
    topk_softmax_k<<<2048, 256, 0, stream>>>(sc, wts + (long)b * 65536,
                                             idxs + (long)b * 65536);
  }
  gather_out_k<<<16384, 256, 0, stream>>>(source, wts, idxs, (float*)d_out);
}